// Round 1
// baseline (1063.099 us; speedup 1.0000x reference)
//
#include <hip/hip_runtime.h>
#include <math.h>

#define B_   2
#define L_   2048
#define D_   1024
#define H_   16
#define G_   4
#define Hd_  64
#define WIN_ 256

typedef float f4 __attribute__((ext_vector_type(4)));

// ln(10000)/32
#define ROPE_LN 0.28782313662425575

// ---------------------------------------------------------------------------
// Kernel 1: fused QKV projection + bias + RoPE.
// C = x(4096x1024) @ [Wq | Wk | Wv](1024x1536). 64x64 tiles, 4x4 micro-tile.
// Stores q (b,h,l,d), k (b,g,l,d), v (b,g,l,d) into workspace.
// ---------------------------------------------------------------------------
__global__ __launch_bounds__(256) void k_qkv_rope(
    const float* __restrict__ x,
    const float* __restrict__ Wq, const float* __restrict__ bq,
    const float* __restrict__ Wk, const float* __restrict__ bk,
    const float* __restrict__ Wv, const float* __restrict__ bv,
    float* __restrict__ qo, float* __restrict__ ko, float* __restrict__ vo)
{
    __shared__ __align__(16) float As[16][68];   // [k][m] transposed
    __shared__ __align__(16) float Bs[16][68];   // [k][n]

    const int tid = threadIdx.x;
    const int tx = tid & 15, ty = tid >> 4;
    const int r0 = blockIdx.x << 6;         // row tile (M = 4096)
    const int c0 = blockIdx.y << 6;         // col tile (N = 1536)

    const float* __restrict__ W;
    const float* __restrict__ bias;
    int ncols, cl0;
    if (c0 < D_)            { W = Wq; bias = bq; ncols = D_;  cl0 = c0; }
    else if (c0 < D_ + 256) { W = Wk; bias = bk; ncols = 256; cl0 = c0 - D_; }
    else                    { W = Wv; bias = bv; ncols = 256; cl0 = c0 - D_ - 256; }

    const int arow = tid >> 2;              // 0..63
    const int akc  = (tid & 3) << 2;        // 0,4,8,12
    const int bkk  = tid >> 4;              // 0..15
    const int bn0  = (tid & 15) << 2;       // 0..60

    float acc[4][4] = {};

    for (int k0 = 0; k0 < D_; k0 += 16) {
        f4 av = *(const f4*)&x[(size_t)(r0 + arow) * D_ + k0 + akc];
        f4 bw = *(const f4*)&W[(size_t)(k0 + bkk) * ncols + cl0 + bn0];
        __syncthreads();
        As[akc + 0][arow] = av[0];
        As[akc + 1][arow] = av[1];
        As[akc + 2][arow] = av[2];
        As[akc + 3][arow] = av[3];
        *(f4*)&Bs[bkk][bn0] = bw;
        __syncthreads();
#pragma unroll
        for (int kk = 0; kk < 16; ++kk) {
            f4 a = *(const f4*)&As[kk][ty << 2];
            f4 b = *(const f4*)&Bs[kk][tx << 2];
#pragma unroll
            for (int i = 0; i < 4; ++i)
#pragma unroll
                for (int j = 0; j < 4; ++j)
                    acc[i][j] += a[i] * b[j];
        }
    }

    const bool doRope = (c0 < D_ + 256);    // q and k segments get RoPE

#pragma unroll
    for (int i = 0; i < 4; ++i) {
        const int r  = r0 + (ty << 2) + i;
        const int bb = r >> 11;             // / L_
        const int l  = r & (L_ - 1);
#pragma unroll
        for (int jp = 0; jp < 2; ++jp) {
            const int c = c0 + (tx << 2) + (jp << 1);   // even global col
            float y0 = acc[i][(jp << 1) + 0] + bias[cl0 + (tx << 2) + (jp << 1) + 0];
            float y1 = acc[i][(jp << 1) + 1] + bias[cl0 + (tx << 2) + (jp << 1) + 1];
            if (doRope) {
                const int dd = c & 63;                  // even, in-head dim
                const int m0 = dd & 31, m1 = (dd + 1) & 31;
                const float if0 = (float)exp(-ROPE_LN * (double)m0);
                const float if1 = (float)exp(-ROPE_LN * (double)m1);
                const float a0 = (float)l * if0;
                const float a1 = (float)l * if1;
                const float sn0 = sinf(a0), cs0 = cosf(a0);
                const float sn1 = sinf(a1), cs1 = cosf(a1);
                const float o0 = y0 * cs0 - y1 * sn0;
                const float o1 = y1 * cs1 + y0 * sn1;
                y0 = o0; y1 = o1;
            }
            if (c < D_) {
                const int h = c >> 6, d = c & 63;
                float* p = qo + (((size_t)bb * H_ + h) * L_ + l) * Hd_ + d;
                p[0] = y0; p[1] = y1;
            } else if (c < D_ + 256) {
                const int g = (c - D_) >> 6, d = c & 63;
                float* p = ko + (((size_t)bb * G_ + g) * L_ + l) * Hd_ + d;
                p[0] = y0; p[1] = y1;
            } else {
                const int g = (c - D_ - 256) >> 6, d = c & 63;
                float* p = vo + (((size_t)bb * G_ + g) * L_ + l) * Hd_ + d;
                p[0] = y0; p[1] = y1;
            }
        }
    }
}

// ---------------------------------------------------------------------------
// Kernel 2: windowed attention, flash-style online softmax.
// One block = 64 queries of one (b,h). Key tiles of 64 within the window
// (|dl|<=256) + one extra pass for the <=4 global columns outside the window.
// Global-row queries are computed (wrong mask) and overwritten by kernel 2b.
// Ks is XOR-swizzled in 16B granules (lanes read different rows -> bank spread).
// ---------------------------------------------------------------------------
__global__ __launch_bounds__(256) void k_attn_win(
    const float* __restrict__ q, const float* __restrict__ kg,
    const float* __restrict__ vg, const int* __restrict__ gpos,
    float* __restrict__ aout)
{
    __shared__ __align__(16) float Qs[64][64];
    __shared__ __align__(16) float Ks[64][64];   // f4-unit col swizzle: c4' = c4 ^ (row&15)
    __shared__ __align__(16) float Vs[64][64];
    __shared__ __align__(16) float Ps[64][64];

    const int tid = threadIdx.x;
    const int tx = tid & 15, ty = tid >> 4;
    const int qt = blockIdx.x;
    const int h  = blockIdx.y;
    const int b  = blockIdx.z;
    const int g  = h >> 2;                  // HPG = 4
    const int q0 = qt << 6;

    const float* qbase = q  + (((size_t)b * H_ + h) * L_ + q0) * Hd_;
    const float* kbase = kg + ((size_t)b * G_ + g) * (size_t)L_ * Hd_;
    const float* vbase = vg + ((size_t)b * G_ + g) * (size_t)L_ * Hd_;

    // stage Q tile, scale folded in
    for (int f = tid; f < 1024; f += 256) {
        f4 t4 = ((const f4*)qbase)[f];
        const int row = f >> 4, cc = (f & 15) << 2;
        Qs[row][cc + 0] = t4[0] * 0.125f;
        Qs[row][cc + 1] = t4[1] * 0.125f;
        Qs[row][cc + 2] = t4[2] * 0.125f;
        Qs[row][cc + 3] = t4[3] * 0.125f;
    }

    // global-column info for this thread (kidx = tx only possible slot)
    int  myg = -0x40000000; bool myginc = false;
    if (tx < 4) {
        myg = gpos[tx];
        bool dup = false;
        for (int j2 = 0; j2 < tx; ++j2) dup = dup || (gpos[j2] == myg);
        myginc = !dup;
    }

    float mrun[4], lrun[4], acc[4][4];
#pragma unroll
    for (int i = 0; i < 4; ++i) {
        mrun[i] = -INFINITY; lrun[i] = 0.f;
#pragma unroll
        for (int j = 0; j < 4; ++j) acc[i][j] = 0.f;
    }

    const int t_lo = (qt - 4 > 0) ? qt - 4 : 0;
    const int t_hi = (qt + 4 < (L_ >> 6) - 1) ? qt + 4 : (L_ >> 6) - 1;
    const int ntiles = t_hi - t_lo + 1;

    for (int tt = 0; tt <= ntiles; ++tt) {
        const bool isWin = (tt < ntiles);
        const int s0 = isWin ? ((t_lo + tt) << 6) : 0;

        __syncthreads();    // previous PV reads done
        if (isWin) {
            const f4* ksrc = (const f4*)(kbase + (size_t)s0 * Hd_);
            const f4* vsrc = (const f4*)(vbase + (size_t)s0 * Hd_);
            for (int f = tid; f < 1024; f += 256) {
                const int row = f >> 4, c4 = f & 15;
                *(f4*)&Ks[row][(c4 ^ (row & 15)) << 2] = ksrc[f];
                *(f4*)&Vs[row][c4 << 2] = vsrc[f];
            }
        } else {
            // load the 4 global K/V rows into rows 0..3
            const int row = tid >> 6, cc = tid & 63;
            const int grow = gpos[row];
            const int kc = ((((cc >> 2) ^ row) << 2) | (cc & 3));   // row&15 == row
            Ks[row][kc] = kbase[(size_t)grow * Hd_ + cc];
            Vs[row][cc] = vbase[(size_t)grow * Hd_ + cc];
        }
        __syncthreads();

        // ---- scores: queries 4ty+i, keys tx+16j ----
        float sc[4][4];
#pragma unroll
        for (int i = 0; i < 4; ++i)
#pragma unroll
            for (int j = 0; j < 4; ++j) sc[i][j] = 0.f;

#pragma unroll
        for (int d0 = 0; d0 < 64; d0 += 4) {
            const int c4s = ((d0 >> 2) ^ tx) << 2;   // swizzled K col
            f4 qa[4], kb[4];
#pragma unroll
            for (int i = 0; i < 4; ++i) qa[i] = *(const f4*)&Qs[(ty << 2) + i][d0];
#pragma unroll
            for (int j = 0; j < 4; ++j) kb[j] = *(const f4*)&Ks[tx + (j << 4)][c4s];
#pragma unroll
            for (int i = 0; i < 4; ++i)
#pragma unroll
                for (int j = 0; j < 4; ++j)
                    sc[i][j] += qa[i][0] * kb[j][0] + qa[i][1] * kb[j][1]
                              + qa[i][2] * kb[j][2] + qa[i][3] * kb[j][3];
        }

        // ---- mask + online softmax update ----
#pragma unroll
        for (int i = 0; i < 4; ++i) {
            const int qpos = q0 + (ty << 2) + i;
            float mx = -INFINITY;
#pragma unroll
            for (int j = 0; j < 4; ++j) {
                bool valid;
                if (isWin) {
                    const int dlt = qpos - (s0 + tx + (j << 4));
                    valid = (dlt <= WIN_) && (dlt >= -WIN_);
                } else if (j == 0 && tx < 4) {
                    const int dlt = qpos - myg;
                    valid = myginc && ((dlt > WIN_) || (dlt < -WIN_));
                } else {
                    valid = false;
                }
                if (!valid) sc[i][j] = -INFINITY;
                mx = fmaxf(mx, sc[i][j]);
            }
            mx = fmaxf(mx, __shfl_xor(mx, 1));
            mx = fmaxf(mx, __shfl_xor(mx, 2));
            mx = fmaxf(mx, __shfl_xor(mx, 4));
            mx = fmaxf(mx, __shfl_xor(mx, 8));

            const float mnew = fmaxf(mrun[i], mx);
            float al;
            if (mnew == -INFINITY) al = 1.f;            // nothing seen yet
            else al = __expf(mrun[i] - mnew);           // mrun=-inf -> 0
            float rs = 0.f;
#pragma unroll
            for (int j = 0; j < 4; ++j) {
                const float p = (sc[i][j] == -INFINITY) ? 0.f : __expf(sc[i][j] - mnew);
                Ps[(ty << 2) + i][tx + (j << 4)] = p;
                rs += p;
            }
            rs += __shfl_xor(rs, 1);
            rs += __shfl_xor(rs, 2);
            rs += __shfl_xor(rs, 4);
            rs += __shfl_xor(rs, 8);
            lrun[i] = lrun[i] * al + rs;
            mrun[i] = mnew;
#pragma unroll
            for (int j = 0; j < 4; ++j) acc[i][j] *= al;
        }
        __syncthreads();    // Ps visible

        // ---- PV: queries 4ty+i, dims 4tx+j ----
        const int kklim = isWin ? 64 : 4;
        for (int kk4 = 0; kk4 < kklim; kk4 += 4) {
            f4 pr[4], vr[4];
#pragma unroll
            for (int i = 0; i < 4; ++i) pr[i] = *(const f4*)&Ps[(ty << 2) + i][kk4];
#pragma unroll
            for (int c = 0; c < 4; ++c) vr[c] = *(const f4*)&Vs[kk4 + c][tx << 2];
#pragma unroll
            for (int i = 0; i < 4; ++i)
#pragma unroll
                for (int j = 0; j < 4; ++j)
                    acc[i][j] += pr[i][0] * vr[0][j] + pr[i][1] * vr[1][j]
                               + pr[i][2] * vr[2][j] + pr[i][3] * vr[3][j];
        }
    }

    // ---- write (b, l, h, d) ----
#pragma unroll
    for (int i = 0; i < 4; ++i) {
        const int l = q0 + (ty << 2) + i;
        const float inv = 1.f / lrun[i];
        f4 o;
        o[0] = acc[i][0] * inv; o[1] = acc[i][1] * inv;
        o[2] = acc[i][2] * inv; o[3] = acc[i][3] * inv;
        *(f4*)(aout + (((size_t)b * L_ + l) * H_ + h) * Hd_ + (tx << 2)) = o;
    }
}

// ---------------------------------------------------------------------------
// Kernel 2b: full-row attention for the <=4 unique global query rows.
// Overwrites kernel 2's output for those rows. One block per (b,h).
// ---------------------------------------------------------------------------
__global__ __launch_bounds__(256) void k_attn_global_rows(
    const float* __restrict__ q, const float* __restrict__ kg,
    const float* __restrict__ vg, const int* __restrict__ gpos,
    float* __restrict__ aout)
{
    __shared__ __align__(16) float qrow[64];
    __shared__ __align__(16) float Ps[L_];
    __shared__ __align__(16) float red[8];
    __shared__ __align__(16) float pacc[16][64];

    const int tid = threadIdx.x;
    const int b = blockIdx.x >> 4;
    const int h = blockIdx.x & 15;
    const int g = h >> 2;
    const float* kbase = kg + ((size_t)b * G_ + g) * (size_t)L_ * Hd_;
    const float* vbase = vg + ((size_t)b * G_ + g) * (size_t)L_ * Hd_;

    for (int gi = 0; gi < 4; ++gi) {
        const int lg = gpos[gi];
        bool dup = false;
        for (int j = 0; j < gi; ++j) dup = dup || (gpos[j] == lg);
        if (dup) continue;                  // block-uniform

        __syncthreads();                    // previous iter fully done
        if (tid < 64)
            qrow[tid] = q[(((size_t)b * H_ + h) * L_ + lg) * Hd_ + tid] * 0.125f;
        __syncthreads();

        // scores for all 2048 keys (global row attends everything)
        float sc[8]; float lmax = -INFINITY;
#pragma unroll
        for (int c = 0; c < 8; ++c) {
            const int s = tid + (c << 8);
            const f4* kr = (const f4*)(kbase + (size_t)s * Hd_);
            float dot = 0.f;
#pragma unroll
            for (int d4 = 0; d4 < 16; ++d4) {
                const f4 kv = kr[d4];
                dot += qrow[(d4 << 2) + 0] * kv[0] + qrow[(d4 << 2) + 1] * kv[1]
                     + qrow[(d4 << 2) + 2] * kv[2] + qrow[(d4 << 2) + 3] * kv[3];
            }
            sc[c] = dot; lmax = fmaxf(lmax, dot);
        }
        for (int o = 32; o; o >>= 1) lmax = fmaxf(lmax, __shfl_xor(lmax, o));
        if ((tid & 63) == 0) red[tid >> 6] = lmax;
        __syncthreads();
        const float M = fmaxf(fmaxf(red[0], red[1]), fmaxf(red[2], red[3]));
        __syncthreads();

        float ls = 0.f;
#pragma unroll
        for (int c = 0; c < 8; ++c) {
            const float p = __expf(sc[c] - M);
            Ps[tid + (c << 8)] = p;
            ls += p;
        }
        for (int o = 32; o; o >>= 1) ls += __shfl_xor(ls, o);
        if ((tid & 63) == 0) red[tid >> 6] = ls;
        __syncthreads();
        const float S = red[0] + red[1] + red[2] + red[3];

        // PV: thread = (f4-col c4, key chunk of 128)
        const int c4 = tid & 15, chunk = tid >> 4;
        f4 a; a[0] = 0.f; a[1] = 0.f; a[2] = 0.f; a[3] = 0.f;
        const int sst = chunk << 7;
        for (int s = sst; s < sst + 128; ++s) {
            const float p = Ps[s];
            const f4 vv = *(const f4*)&vbase[(size_t)s * Hd_ + (c4 << 2)];
            a[0] += p * vv[0]; a[1] += p * vv[1]; a[2] += p * vv[2]; a[3] += p * vv[3];
        }
        *(f4*)&pacc[chunk][c4 << 2] = a;
        __syncthreads();
        if (tid < 64) {
            float s = 0.f;
#pragma unroll
            for (int cch = 0; cch < 16; ++cch) s += pacc[cch][tid];
            aout[(((size_t)b * L_ + lg) * H_ + h) * Hd_ + tid] = s / S;
        }
    }
}

// ---------------------------------------------------------------------------
// Kernel 3: output projection out = attn(4096x1024) @ Wo + bo
// ---------------------------------------------------------------------------
__global__ __launch_bounds__(256) void k_outproj(
    const float* __restrict__ A, const float* __restrict__ W,
    const float* __restrict__ bias, float* __restrict__ out)
{
    __shared__ __align__(16) float As[16][68];
    __shared__ __align__(16) float Bs[16][68];

    const int tid = threadIdx.x;
    const int tx = tid & 15, ty = tid >> 4;
    const int r0 = blockIdx.x << 6;
    const int c0 = blockIdx.y << 6;

    const int arow = tid >> 2;
    const int akc  = (tid & 3) << 2;
    const int bkk  = tid >> 4;
    const int bn0  = (tid & 15) << 2;

    float acc[4][4] = {};

    for (int k0 = 0; k0 < D_; k0 += 16) {
        f4 av = *(const f4*)&A[(size_t)(r0 + arow) * D_ + k0 + akc];
        f4 bw = *(const f4*)&W[(size_t)(k0 + bkk) * D_ + c0 + bn0];
        __syncthreads();
        As[akc + 0][arow] = av[0];
        As[akc + 1][arow] = av[1];
        As[akc + 2][arow] = av[2];
        As[akc + 3][arow] = av[3];
        *(f4*)&Bs[bkk][bn0] = bw;
        __syncthreads();
#pragma unroll
        for (int kk = 0; kk < 16; ++kk) {
            f4 a = *(const f4*)&As[kk][ty << 2];
            f4 b = *(const f4*)&Bs[kk][tx << 2];
#pragma unroll
            for (int i = 0; i < 4; ++i)
#pragma unroll
                for (int j = 0; j < 4; ++j)
                    acc[i][j] += a[i] * b[j];
        }
    }

#pragma unroll
    for (int i = 0; i < 4; ++i) {
        const int r = r0 + (ty << 2) + i;
        float* p = out + (size_t)r * D_ + c0 + (tx << 2);
#pragma unroll
        for (int j = 0; j < 4; ++j) p[j] = acc[i][j] + bias[c0 + (tx << 2) + j];
    }
}

// ---------------------------------------------------------------------------
extern "C" void kernel_launch(void* const* d_in, const int* in_sizes, int n_in,
                              void* d_out, int out_size, void* d_ws, size_t ws_size,
                              hipStream_t stream)
{
    const float* x  = (const float*)d_in[0];
    const int*   gp = (const int*)d_in[1];
    const float* Wq = (const float*)d_in[2];
    const float* bq = (const float*)d_in[3];
    const float* Wk = (const float*)d_in[4];
    const float* bk = (const float*)d_in[5];
    const float* Wv = (const float*)d_in[6];
    const float* bv = (const float*)d_in[7];
    const float* Wo = (const float*)d_in[8];
    const float* bo = (const float*)d_in[9];
    float* out = (float*)d_out;

    float* qws = (float*)d_ws;                                  // B*H*L*Hd
    float* kws = qws + (size_t)B_ * H_ * L_ * Hd_;              // B*G*L*Hd
    float* vws = kws + (size_t)B_ * G_ * L_ * Hd_;              // B*G*L*Hd
    float* aws = vws + (size_t)B_ * G_ * L_ * Hd_;              // B*L*D

    k_qkv_rope<<<dim3(64, 24), 256, 0, stream>>>(x, Wq, bq, Wk, bk, Wv, bv,
                                                 qws, kws, vws);
    k_attn_win<<<dim3(32, 16, 2), 256, 0, stream>>>(qws, kws, vws, gp, aws);
    k_attn_global_rows<<<dim3(32), 256, 0, stream>>>(qws, kws, vws, gp, aws);
    k_outproj<<<dim3(64, 16), 256, 0, stream>>>(aws, Wo, bo, out);
}

// Round 2
// 458.498 us; speedup vs baseline: 2.3187x; 2.3187x over previous
//
#include <hip/hip_runtime.h>
#include <math.h>

#define B_   2
#define L_   2048
#define D_   1024
#define H_   16
#define G_   4
#define Hd_  64
#define WIN_ 256

typedef float f4 __attribute__((ext_vector_type(4)));
typedef float f32x4 __attribute__((ext_vector_type(4)));
typedef short s16x8 __attribute__((ext_vector_type(8)));

// ln(10000)/32
#define ROPE_LN 0.28782313662425575

__device__ __forceinline__ float bf2f(ushort u) {
    union { uint i; float f; } c; c.i = ((uint)u) << 16; return c.f;
}
__device__ __forceinline__ ushort f2bf(float f) {
    union { float f; uint i; } c; c.f = f;
    return (ushort)((c.i + 0x7FFFu + ((c.i >> 16) & 1u)) >> 16);
}

// ---------------------------------------------------------------------------
// Kernel 1: fused QKV projection + bias + RoPE.  fp32 GEMM, bf16 outputs:
//   Q (b,h,l,d) bf16 pre-scaled by 1/8;  K (b,g,l,d) bf16;  V^T (b,g,d,l) bf16.
// ---------------------------------------------------------------------------
__global__ __launch_bounds__(256) void k_qkv_rope(
    const float* __restrict__ x,
    const float* __restrict__ Wq, const float* __restrict__ bq,
    const float* __restrict__ Wk, const float* __restrict__ bk,
    const float* __restrict__ Wv, const float* __restrict__ bv,
    ushort* __restrict__ qo, ushort* __restrict__ ko, ushort* __restrict__ vt)
{
    __shared__ __align__(16) float As[16][68];
    __shared__ __align__(16) float Bs[16][68];

    const int tid = threadIdx.x;
    const int tx = tid & 15, ty = tid >> 4;
    const int r0 = blockIdx.x << 6;
    const int c0 = blockIdx.y << 6;

    const float* __restrict__ W;
    const float* __restrict__ bias;
    int ncols, cl0;
    if (c0 < D_)            { W = Wq; bias = bq; ncols = D_;  cl0 = c0; }
    else if (c0 < D_ + 256) { W = Wk; bias = bk; ncols = 256; cl0 = c0 - D_; }
    else                    { W = Wv; bias = bv; ncols = 256; cl0 = c0 - D_ - 256; }

    const int arow = tid >> 2;
    const int akc  = (tid & 3) << 2;
    const int bkk  = tid >> 4;
    const int bn0  = (tid & 15) << 2;

    float acc[4][4] = {};

    for (int k0 = 0; k0 < D_; k0 += 16) {
        f4 av = *(const f4*)&x[(size_t)(r0 + arow) * D_ + k0 + akc];
        f4 bw = *(const f4*)&W[(size_t)(k0 + bkk) * ncols + cl0 + bn0];
        __syncthreads();
        As[akc + 0][arow] = av[0];
        As[akc + 1][arow] = av[1];
        As[akc + 2][arow] = av[2];
        As[akc + 3][arow] = av[3];
        *(f4*)&Bs[bkk][bn0] = bw;
        __syncthreads();
#pragma unroll
        for (int kk = 0; kk < 16; ++kk) {
            f4 a = *(const f4*)&As[kk][ty << 2];
            f4 b = *(const f4*)&Bs[kk][tx << 2];
#pragma unroll
            for (int i = 0; i < 4; ++i)
#pragma unroll
                for (int j = 0; j < 4; ++j)
                    acc[i][j] += a[i] * b[j];
        }
    }

    const bool doRope = (c0 < D_ + 256);

#pragma unroll
    for (int i = 0; i < 4; ++i) {
        const int r  = r0 + (ty << 2) + i;
        const int bb = r >> 11;
        const int l  = r & (L_ - 1);
#pragma unroll
        for (int jp = 0; jp < 2; ++jp) {
            const int c = c0 + (tx << 2) + (jp << 1);
            float y0 = acc[i][(jp << 1) + 0] + bias[cl0 + (tx << 2) + (jp << 1) + 0];
            float y1 = acc[i][(jp << 1) + 1] + bias[cl0 + (tx << 2) + (jp << 1) + 1];
            if (doRope) {
                const int dd = c & 63;
                const int m0 = dd & 31, m1 = (dd + 1) & 31;
                const float if0 = (float)exp(-ROPE_LN * (double)m0);  // loop-invariant, hoisted
                const float if1 = (float)exp(-ROPE_LN * (double)m1);
                const float a0 = (float)l * if0;
                const float a1 = (float)l * if1;
                const float sn0 = sinf(a0), cs0 = cosf(a0);
                const float sn1 = sinf(a1), cs1 = cosf(a1);
                const float o0 = y0 * cs0 - y1 * sn0;
                const float o1 = y1 * cs1 + y0 * sn1;
                y0 = o0; y1 = o1;
            }
            if (c < D_) {
                const int h = c >> 6, d = c & 63;
                ushort* p = qo + (((size_t)bb * H_ + h) * L_ + l) * Hd_ + d;
                p[0] = f2bf(y0 * 0.125f); p[1] = f2bf(y1 * 0.125f);
            } else if (c < D_ + 256) {
                const int g = (c - D_) >> 6, d = c & 63;
                ushort* p = ko + (((size_t)bb * G_ + g) * L_ + l) * Hd_ + d;
                p[0] = f2bf(y0); p[1] = f2bf(y1);
            } else {
                const int g = (c - D_ - 256) >> 6, d = c & 63;
                vt[(((size_t)bb * G_ + g) * Hd_ + d    ) * L_ + l] = f2bf(y0);
                vt[(((size_t)bb * G_ + g) * Hd_ + d + 1) * L_ + l] = f2bf(y1);
            }
        }
    }
}

// ---------------------------------------------------------------------------
// Kernel 2: windowed flash attention, bf16 MFMA (16x16x32), no __syncthreads.
// Block = 256 thr = 4 waves; wave w owns 16 query rows of one 64-q tile.
// Fragments (Q,K,V^T) load directly from global bf16; only P goes via LDS
// (per-wave 16x64 bf16, XOR-swizzled).  Global-col keys = one masked
// pseudo-tile.  Global-row queries overwritten later by kernel 2b.
// MFMA frag layout (m92-verified): A/B lane l -> row l%16, k=(l>>4)*8+j;
// C/D lane l -> col l&15, row (l>>4)*4+reg.
// ---------------------------------------------------------------------------
__global__ __launch_bounds__(256, 3) void k_attn_win(
    const ushort* __restrict__ qb, const ushort* __restrict__ kb,
    const ushort* __restrict__ vtb, const int* __restrict__ gpos,
    float* __restrict__ aout)
{
    __shared__ ushort Pl[4][1024];   // per-wave 16 rows x 64 keys, swizzled

    const int tid  = threadIdx.x;
    const int wv   = tid >> 6, lane = tid & 63;
    const int lr   = lane & 15, lg = lane >> 4;
    const int qt = blockIdx.x, h = blockIdx.y, b = blockIdx.z;
    const int g  = h >> 2;
    const int q0w = (qt << 6) + (wv << 4);

    const ushort* qp = qb  + (((size_t)b * H_ + h) * L_ + q0w) * Hd_;
    const ushort* kp = kb  + ((size_t)b * G_ + g) * (size_t)L_ * Hd_;
    const ushort* vp = vtb + ((size_t)b * G_ + g) * (size_t)Hd_ * L_;
    char* pbase = (char*)&Pl[wv][0];

    // Q fragments (reused across all tiles)
    const s16x8* qr = (const s16x8*)(qp + (size_t)lr * Hd_);
    const s16x8 qf0 = qr[lg], qf1 = qr[lg + 4];

    int gall[4];
#pragma unroll
    for (int j = 0; j < 4; ++j) gall[j] = gpos[j];
    const int myg = gall[lr & 3];
    int gvalid = 0;
    if (lr < 4) {
        bool dup = false;
        for (int j = 0; j < lr; ++j) dup = dup || (gall[j] == myg);
        gvalid = !dup;
    }

    f32x4 acc_o[4];
#pragma unroll
    for (int j = 0; j < 4; ++j) acc_o[j] = (f32x4)0.f;
    f32x4 mrun = (f32x4)(-INFINITY);
    f32x4 lrun = (f32x4)0.f;

    const int t_lo = (qt - 4 > 0) ? qt - 4 : 0;
    const int t_hi = (qt + 4 < (L_ >> 6) - 1) ? qt + 4 : (L_ >> 6) - 1;
    const int ntiles = t_hi - t_lo + 1;

    for (int tt = 0; tt <= ntiles; ++tt) {
        const bool isWin = (tt < ntiles);
        const int s0 = (t_lo + tt) << 6;

        // ---- QK^T scores ----
        f32x4 s[4];
        if (isWin) {
#pragma unroll
            for (int gk = 0; gk < 4; ++gk) {
                const s16x8* kr = (const s16x8*)(kp + ((size_t)s0 + gk * 16 + lr) * Hd_);
                s16x8 kf0 = kr[lg], kf1 = kr[lg + 4];
                f32x4 t = __builtin_amdgcn_mfma_f32_16x16x32_bf16(qf0, kf0, (f32x4)0.f, 0, 0, 0);
                s[gk]   = __builtin_amdgcn_mfma_f32_16x16x32_bf16(qf1, kf1, t, 0, 0, 0);
            }
        } else {
            const s16x8* kr = (const s16x8*)(kp + (size_t)myg * Hd_);
            s16x8 kf0 = kr[lg], kf1 = kr[lg + 4];
            f32x4 t = __builtin_amdgcn_mfma_f32_16x16x32_bf16(qf0, kf0, (f32x4)0.f, 0, 0, 0);
            s[0]    = __builtin_amdgcn_mfma_f32_16x16x32_bf16(qf1, kf1, t, 0, 0, 0);
            s[1] = (f32x4)0.f; s[2] = (f32x4)0.f; s[3] = (f32x4)0.f;
        }

        // ---- mask ----
#pragma unroll
        for (int gk = 0; gk < 4; ++gk) {
#pragma unroll
            for (int r = 0; r < 4; ++r) {
                const int qpos = q0w + lg * 4 + r;
                bool valid;
                if (isWin) {
                    const int dlt = qpos - (s0 + gk * 16 + lr);
                    valid = (dlt <= WIN_) && (dlt >= -WIN_);
                } else if (gk == 0) {
                    const int dlt = qpos - myg;
                    valid = gvalid && ((dlt > WIN_) || (dlt < -WIN_));
                } else {
                    valid = false;
                }
                if (!valid) s[gk][r] = -INFINITY;
            }
        }

        // ---- online softmax (per q-row = per C-reg) ----
        f32x4 al4;
#pragma unroll
        for (int r = 0; r < 4; ++r) {
            float mx = fmaxf(fmaxf(s[0][r], s[1][r]), fmaxf(s[2][r], s[3][r]));
            mx = fmaxf(mx, __shfl_xor(mx, 1));
            mx = fmaxf(mx, __shfl_xor(mx, 2));
            mx = fmaxf(mx, __shfl_xor(mx, 4));
            mx = fmaxf(mx, __shfl_xor(mx, 8));
            const float mn = fmaxf(mrun[r], mx);
            const float al = (mn == -INFINITY) ? 1.f : __expf(mrun[r] - mn);
            const int row = lg * 4 + r;
            const int swz = (row & 7) << 4;
            float rs = 0.f;
#pragma unroll
            for (int gk = 0; gk < 4; ++gk) {
                const float sv = s[gk][r];
                const float p = (sv == -INFINITY) ? 0.f : __expf(sv - mn);
                const int key = gk * 16 + lr;
                *(ushort*)(pbase + (((row << 7) + (key << 1)) ^ swz)) = f2bf(p);
                rs += p;
            }
            rs += __shfl_xor(rs, 1);
            rs += __shfl_xor(rs, 2);
            rs += __shfl_xor(rs, 4);
            rs += __shfl_xor(rs, 8);
            lrun[r] = lrun[r] * al + rs;
            mrun[r] = mn;
            al4[r] = al;
        }
#pragma unroll
        for (int j = 0; j < 4; ++j) acc_o[j] *= al4;

        // ---- PV ----
        const int pswz = (lr & 7) << 4;
        const s16x8 pa0 = *(const s16x8*)(pbase + (((lr << 7) + (lg << 4)     ) ^ pswz));
        if (isWin) {
            const s16x8 pa1 = *(const s16x8*)(pbase + (((lr << 7) + 64 + (lg << 4)) ^ pswz));
#pragma unroll
            for (int dg = 0; dg < 4; ++dg) {
                const s16x8* vr = (const s16x8*)(vp + (size_t)(dg * 16 + lr) * L_ + s0);
                s16x8 vb0 = vr[lg], vb1 = vr[lg + 4];
                acc_o[dg] = __builtin_amdgcn_mfma_f32_16x16x32_bf16(pa0, vb0, acc_o[dg], 0, 0, 0);
                acc_o[dg] = __builtin_amdgcn_mfma_f32_16x16x32_bf16(pa1, vb1, acc_o[dg], 0, 0, 0);
            }
        } else {
#pragma unroll
            for (int dg = 0; dg < 4; ++dg) {
                s16x8 vb0 = (s16x8)(short)0;
                if (lg == 0) {
#pragma unroll
                    for (int j = 0; j < 4; ++j)
                        vb0[j] = (short)vp[(size_t)(dg * 16 + lr) * L_ + gall[j]];
                }
                acc_o[dg] = __builtin_amdgcn_mfma_f32_16x16x32_bf16(pa0, vb0, acc_o[dg], 0, 0, 0);
            }
        }
    }

    // ---- write output (b,l,h,d) fp32 ----
#pragma unroll
    for (int r = 0; r < 4; ++r) {
        const float inv = 1.f / lrun[r];
        const int qrow = q0w + lg * 4 + r;
        float* op = aout + (((size_t)b * L_ + qrow) * H_ + h) * Hd_;
#pragma unroll
        for (int dg = 0; dg < 4; ++dg) op[dg * 16 + lr] = acc_o[dg][r] * inv;
    }
}

// ---------------------------------------------------------------------------
// Kernel 2b: full-row attention for the <=4 unique global query rows (bf16 in).
// ---------------------------------------------------------------------------
__global__ __launch_bounds__(256) void k_attn_global_rows(
    const ushort* __restrict__ q, const ushort* __restrict__ kg,
    const ushort* __restrict__ vt, const int* __restrict__ gpos,
    float* __restrict__ aout)
{
    __shared__ float qrow[64];
    __shared__ float Ps[L_];
    __shared__ float red[4];
    __shared__ float pacc[4][64];

    const int tid = threadIdx.x;
    const int wv = tid >> 6, lane = tid & 63;
    const int b = blockIdx.x >> 4;
    const int h = blockIdx.x & 15;
    const int g = h >> 2;
    const ushort* kbase = kg + ((size_t)b * G_ + g) * (size_t)L_ * Hd_;
    const ushort* vbase = vt + ((size_t)b * G_ + g) * (size_t)Hd_ * L_;

    for (int gi = 0; gi < 4; ++gi) {
        const int lq = gpos[gi];
        bool dup = false;
        for (int j = 0; j < gi; ++j) dup = dup || (gpos[j] == lq);
        if (dup) continue;                      // block-uniform

        __syncthreads();
        if (tid < 64) qrow[tid] = bf2f(q[(((size_t)b * H_ + h) * L_ + lq) * Hd_ + tid]); // pre-scaled
        __syncthreads();

        float sc[8]; float lmax = -INFINITY;
#pragma unroll
        for (int c = 0; c < 8; ++c) {
            const int s = tid + (c << 8);
            const s16x8* kr = (const s16x8*)(kbase + (size_t)s * Hd_);
            float dot = 0.f;
#pragma unroll
            for (int d8 = 0; d8 < 8; ++d8) {
                s16x8 kv = kr[d8];
#pragma unroll
                for (int j = 0; j < 8; ++j) dot += qrow[d8 * 8 + j] * bf2f((ushort)kv[j]);
            }
            sc[c] = dot; lmax = fmaxf(lmax, dot);
        }
#pragma unroll
        for (int o = 32; o; o >>= 1) lmax = fmaxf(lmax, __shfl_xor(lmax, o));
        if (lane == 0) red[wv] = lmax;
        __syncthreads();
        const float M = fmaxf(fmaxf(red[0], red[1]), fmaxf(red[2], red[3]));
        __syncthreads();

        float ls = 0.f;
#pragma unroll
        for (int c = 0; c < 8; ++c) {
            const float p = __expf(sc[c] - M);
            Ps[tid + (c << 8)] = p;
            ls += p;
        }
#pragma unroll
        for (int o = 32; o; o >>= 1) ls += __shfl_xor(ls, o);
        if (lane == 0) red[wv] = ls;
        __syncthreads();
        const float S = red[0] + red[1] + red[2] + red[3];

        // PV: thread = (dim d, key-chunk of 512) over V^T rows
        const int d = tid & 63, ch = tid >> 6;
        const ushort* vr = vbase + (size_t)d * L_ + (ch << 9);
        float a = 0.f;
        for (int s8 = 0; s8 < 64; ++s8) {
            s16x8 vv = ((const s16x8*)vr)[s8];
            const float* pp = &Ps[(ch << 9) + (s8 << 3)];
#pragma unroll
            for (int j = 0; j < 8; ++j) a += pp[j] * bf2f((ushort)vv[j]);
        }
        pacc[ch][d] = a;
        __syncthreads();
        if (tid < 64) {
            const float sum = pacc[0][tid] + pacc[1][tid] + pacc[2][tid] + pacc[3][tid];
            aout[(((size_t)b * L_ + lq) * H_ + h) * Hd_ + tid] = sum / S;
        }
        __syncthreads();
    }
}

// ---------------------------------------------------------------------------
// Kernel 3: output projection out = attn(4096x1024) @ Wo + bo   (fp32)
// ---------------------------------------------------------------------------
__global__ __launch_bounds__(256) void k_outproj(
    const float* __restrict__ A, const float* __restrict__ W,
    const float* __restrict__ bias, float* __restrict__ out)
{
    __shared__ __align__(16) float As[16][68];
    __shared__ __align__(16) float Bs[16][68];

    const int tid = threadIdx.x;
    const int tx = tid & 15, ty = tid >> 4;
    const int r0 = blockIdx.x << 6;
    const int c0 = blockIdx.y << 6;

    const int arow = tid >> 2;
    const int akc  = (tid & 3) << 2;
    const int bkk  = tid >> 4;
    const int bn0  = (tid & 15) << 2;

    float acc[4][4] = {};

    for (int k0 = 0; k0 < D_; k0 += 16) {
        f4 av = *(const f4*)&A[(size_t)(r0 + arow) * D_ + k0 + akc];
        f4 bw = *(const f4*)&W[(size_t)(k0 + bkk) * D_ + c0 + bn0];
        __syncthreads();
        As[akc + 0][arow] = av[0];
        As[akc + 1][arow] = av[1];
        As[akc + 2][arow] = av[2];
        As[akc + 3][arow] = av[3];
        *(f4*)&Bs[bkk][bn0] = bw;
        __syncthreads();
#pragma unroll
        for (int kk = 0; kk < 16; ++kk) {
            f4 a = *(const f4*)&As[kk][ty << 2];
            f4 b = *(const f4*)&Bs[kk][tx << 2];
#pragma unroll
            for (int i = 0; i < 4; ++i)
#pragma unroll
                for (int j = 0; j < 4; ++j)
                    acc[i][j] += a[i] * b[j];
        }
    }

#pragma unroll
    for (int i = 0; i < 4; ++i) {
        const int r = r0 + (ty << 2) + i;
        float* p = out + (size_t)r * D_ + c0 + (tx << 2);
#pragma unroll
        for (int j = 0; j < 4; ++j) p[j] = acc[i][j] + bias[c0 + (tx << 2) + j];
    }
}

// ---------------------------------------------------------------------------
extern "C" void kernel_launch(void* const* d_in, const int* in_sizes, int n_in,
                              void* d_out, int out_size, void* d_ws, size_t ws_size,
                              hipStream_t stream)
{
    const float* x  = (const float*)d_in[0];
    const int*   gp = (const int*)d_in[1];
    const float* Wq = (const float*)d_in[2];
    const float* bq = (const float*)d_in[3];
    const float* Wk = (const float*)d_in[4];
    const float* bk = (const float*)d_in[5];
    const float* Wv = (const float*)d_in[6];
    const float* bv = (const float*)d_in[7];
    const float* Wo = (const float*)d_in[8];
    const float* bo = (const float*)d_in[9];
    float* out = (float*)d_out;

    ushort* qws = (ushort*)d_ws;                         // B*H*L*Hd bf16 (8 MB)
    ushort* kws = qws + (size_t)B_ * H_ * L_ * Hd_;      // B*G*L*Hd bf16 (2 MB)
    ushort* vtws = kws + (size_t)B_ * G_ * L_ * Hd_;     // B*G*Hd*L bf16 (2 MB)
    float*  aws = (float*)(vtws + (size_t)B_ * G_ * L_ * Hd_);  // B*L*D f32 (16 MB)

    k_qkv_rope<<<dim3(64, 24), 256, 0, stream>>>(x, Wq, bq, Wk, bk, Wv, bv,
                                                 qws, kws, vtws);
    k_attn_win<<<dim3(32, 16, 2), 256, 0, stream>>>(qws, kws, vtws, gp, aws);
    k_attn_global_rows<<<dim3(32), 256, 0, stream>>>(qws, kws, vtws, gp, aws);
    k_outproj<<<dim3(64, 16), 256, 0, stream>>>(aws, Wo, bo, out);
}

// Round 3
// 227.229 us; speedup vs baseline: 4.6785x; 2.0178x over previous
//
#include <hip/hip_runtime.h>
#include <math.h>

#define B_   2
#define L_   2048
#define D_   1024
#define H_   16
#define G_   4
#define Hd_  64
#define WIN_ 256

typedef float f4 __attribute__((ext_vector_type(4)));
typedef float f32x4 __attribute__((ext_vector_type(4)));
typedef short s16x8 __attribute__((ext_vector_type(8)));
typedef ushort u16x4 __attribute__((ext_vector_type(4)));

// ln(10000)/32
#define ROPE_LN 0.28782313662425575

__device__ __forceinline__ float bf2f(ushort u) {
    union { uint i; float f; } c; c.i = ((uint)u) << 16; return c.f;
}
__device__ __forceinline__ ushort f2bf(float f) {
    union { float f; uint i; } c; c.f = f;
    return (ushort)((c.i + 0x7FFFu + ((c.i >> 16) & 1u)) >> 16);
}

// ---------------------------------------------------------------------------
// Prep: cast x (fp32 -> bf16), 4 elems/thread
// ---------------------------------------------------------------------------
__global__ __launch_bounds__(256) void k_prep_x(const float* __restrict__ x,
                                                ushort* __restrict__ xb)
{
    const int idx = blockIdx.x * 256 + threadIdx.x;   // 1M threads
    f4 v = ((const f4*)x)[idx];
    u16x4 o;
    o[0] = f2bf(v[0]); o[1] = f2bf(v[1]); o[2] = f2bf(v[2]); o[3] = f2bf(v[3]);
    ((u16x4*)xb)[idx] = o;
}

// ---------------------------------------------------------------------------
// Prep: transpose+cast weights.  z=0:Wq  z=1:Wk  z=2:Wv  -> Wt[1536][1024]
//                                z=3:Wo -> Wot[1024][1024]
// ---------------------------------------------------------------------------
__global__ __launch_bounds__(256) void k_prep_w(
    const float* __restrict__ Wq, const float* __restrict__ Wk,
    const float* __restrict__ Wv, const float* __restrict__ Wo,
    ushort* __restrict__ Wt, ushort* __restrict__ Wot)
{
    __shared__ __align__(16) float Ts[64][68];
    const int z = blockIdx.z;
    const float* W; ushort* dst; int N, rowoff;
    if (z == 0)      { W = Wq; N = 1024; dst = Wt;  rowoff = 0;    }
    else if (z == 1) { W = Wk; N = 256;  dst = Wt;  rowoff = 1024; }
    else if (z == 2) { W = Wv; N = 256;  dst = Wt;  rowoff = 1280; }
    else             { W = Wo; N = 1024; dst = Wot; rowoff = 0;    }
    const int k0 = blockIdx.x << 6;
    const int n0 = blockIdx.y << 6;
    if (n0 >= N) return;
    const int tid = threadIdx.x;
    const int rr = tid >> 4, cc4 = (tid & 15) << 2;
#pragma unroll
    for (int i = 0; i < 4; ++i) {
        const int r = rr + i * 16;
        *(f4*)&Ts[r][cc4] = *(const f4*)&W[(size_t)(k0 + r) * N + n0 + cc4];
    }
    __syncthreads();
#pragma unroll
    for (int i = 0; i < 4; ++i) {
        const int tr = rr + i * 16;          // n index
        u16x4 pk;
#pragma unroll
        for (int j = 0; j < 4; ++j) pk[j] = f2bf(Ts[cc4 + j][tr]);
        *(u16x4*)&dst[(size_t)(rowoff + n0 + tr) * 1024 + k0 + cc4] = pk;
    }
}

// ---------------------------------------------------------------------------
// Prep: RoPE sin/cos table  sct[l][m]=cos, sct[l][32+m]=sin  (l<2048, m<32)
// ---------------------------------------------------------------------------
__global__ __launch_bounds__(256) void k_prep_sc(float* __restrict__ sct)
{
    const int idx = blockIdx.x * 256 + threadIdx.x;   // 64K
    const int l = idx >> 5, m = idx & 31;
    const float invf = (float)exp(-ROPE_LN * (double)m);
    const float a = (float)l * invf;
    sct[l * 64 + m]      = cosf(a);
    sct[l * 64 + 32 + m] = sinf(a);
}

// ---------------------------------------------------------------------------
// bf16 MFMA GEMM: C[M,N] = A[M,K=1024] @ Bt[N,K]^T.  128x128 tile, BK=32,
// 4 waves (2x2), 4x4 16x16x32 frags/wave.  Reg-staged LDS, XOR slot swizzle.
// mode 0: QKV epilogue (bias + 1/8 q scale + scatter q/k/Vt bf16)
// mode 1: out-proj epilogue (bias + fp32 store)
// ---------------------------------------------------------------------------
__global__ __launch_bounds__(256) void k_gemm_bf16(
    const ushort* __restrict__ A, const ushort* __restrict__ Bt, int mode,
    const float* __restrict__ b0, const float* __restrict__ b1,
    const float* __restrict__ b2,
    ushort* __restrict__ qo, ushort* __restrict__ ko, ushort* __restrict__ vt,
    float* __restrict__ outp)
{
    __shared__ __align__(16) ushort As[4096];   // [128 rows][32 k] 64B/row
    __shared__ __align__(16) ushort Bs[4096];

    const int tid = threadIdx.x;
    const int wv = tid >> 6, lane = tid & 63, lr = lane & 15, lg = lane >> 4;
    const int wm = wv >> 1, wn = wv & 1;
    const int rblk = blockIdx.x << 7, cblk = blockIdx.y << 7;

    // staging: thread covers rows sr and sr+64, k-slot ss (8 bf16 = 16B)
    const int sr = tid >> 2, ss = tid & 3;
    const int sr2 = sr + 64;
    const size_t aoff = (size_t)(rblk + sr) * 1024 + ss * 8;
    const size_t boff = (size_t)(cblk + sr) * 1024 + ss * 8;
    const int wb0 = sr * 64 + ((ss ^ ((sr >> 1) & 3)) << 4);
    const int wb1 = sr2 * 64 + ((ss ^ ((sr2 >> 1) & 3)) << 4);

    f32x4 acc[4][4];
#pragma unroll
    for (int m = 0; m < 4; ++m)
#pragma unroll
        for (int n = 0; n < 4; ++n) acc[m][n] = (f32x4)0.f;

    f4 a0 = *(const f4*)(A + aoff);
    f4 a1 = *(const f4*)(A + aoff + 64 * 1024);
    f4 c0 = *(const f4*)(Bt + boff);
    f4 c1 = *(const f4*)(Bt + boff + 64 * 1024);

    for (int kt = 0; kt < 32; ++kt) {
        __syncthreads();                       // prev LDS reads done
        *(f4*)((char*)As + wb0) = a0;
        *(f4*)((char*)As + wb1) = a1;
        *(f4*)((char*)Bs + wb0) = c0;
        *(f4*)((char*)Bs + wb1) = c1;
        __syncthreads();
        if (kt < 31) {
            const size_t ko_ = (size_t)(kt + 1) * 32;
            a0 = *(const f4*)(A + aoff + ko_);
            a1 = *(const f4*)(A + aoff + 64 * 1024 + ko_);
            c0 = *(const f4*)(Bt + boff + ko_);
            c1 = *(const f4*)(Bt + boff + 64 * 1024 + ko_);
        }
        s16x8 aF[4], bF[4];
#pragma unroll
        for (int m = 0; m < 4; ++m) {
            const int r = wm * 64 + m * 16 + lr;
            aF[m] = *(const s16x8*)((char*)As + r * 64 + ((lg ^ ((r >> 1) & 3)) << 4));
        }
#pragma unroll
        for (int n = 0; n < 4; ++n) {
            const int r = wn * 64 + n * 16 + lr;
            bF[n] = *(const s16x8*)((char*)Bs + r * 64 + ((lg ^ ((r >> 1) & 3)) << 4));
        }
#pragma unroll
        for (int m = 0; m < 4; ++m)
#pragma unroll
            for (int n = 0; n < 4; ++n)
                acc[m][n] = __builtin_amdgcn_mfma_f32_16x16x32_bf16(aF[m], bF[n], acc[m][n], 0, 0, 0);
    }

    // ---- epilogue ----  C row = rblk+wm*64+m*16+lg*4+rg, col = cblk+wn*64+n*16+lr
    if (mode == 0) {
#pragma unroll
        for (int m = 0; m < 4; ++m) {
            const int row = rblk + wm * 64 + m * 16 + (lg << 2);
            const int bb = row >> 11, l = row & 2047;
#pragma unroll
            for (int n = 0; n < 4; ++n) {
                const int col = cblk + wn * 64 + n * 16 + lr;
                if (col < 1024) {
                    const int h = col >> 6, d = col & 63;
                    const float bi = b0[col];
                    ushort* p = qo + (((size_t)(bb * 16 + h)) * 2048 + l) * 64 + d;
#pragma unroll
                    for (int rg = 0; rg < 4; ++rg)
                        p[(size_t)rg * 64] = f2bf((acc[m][n][rg] + bi) * 0.125f);
                } else if (col < 1280) {
                    const int cl = col - 1024, g = cl >> 6, d = cl & 63;
                    const float bi = b1[cl];
                    ushort* p = ko + (((size_t)(bb * 4 + g)) * 2048 + l) * 64 + d;
#pragma unroll
                    for (int rg = 0; rg < 4; ++rg)
                        p[(size_t)rg * 64] = f2bf(acc[m][n][rg] + bi);
                } else {
                    const int cl = col - 1280, g = cl >> 6, d = cl & 63;
                    const float bi = b2[cl];
                    u16x4 pk;
#pragma unroll
                    for (int rg = 0; rg < 4; ++rg) pk[rg] = f2bf(acc[m][n][rg] + bi);
                    *(u16x4*)(vt + ((size_t)(bb * 4 + g) * 64 + d) * 2048 + l) = pk;
                }
            }
        }
    } else {
#pragma unroll
        for (int m = 0; m < 4; ++m) {
            const int row = rblk + wm * 64 + m * 16 + (lg << 2);
#pragma unroll
            for (int n = 0; n < 4; ++n) {
                const int col = cblk + wn * 64 + n * 16 + lr;
                const float bi = b0[col];
#pragma unroll
                for (int rg = 0; rg < 4; ++rg)
                    outp[(size_t)(row + rg) * 1024 + col] = acc[m][n][rg] + bi;
            }
        }
    }
}

// ---------------------------------------------------------------------------
// RoPE (table-driven), in-place on q then k.  8 elems (4 pairs)/thread.
// ---------------------------------------------------------------------------
__global__ __launch_bounds__(256) void k_rope(ushort* __restrict__ q,
                                              ushort* __restrict__ k,
                                              const float* __restrict__ sct)
{
    const int idx = blockIdx.x * 256 + threadIdx.x;
    const int QU = (B_ * H_ * L_ * Hd_) / 8;          // 524288
    ushort* p; int l, d0;
    if (idx < QU) {
        p = q + (size_t)idx * 8;
        l = (idx >> 3) & 2047;
        d0 = (idx & 7) << 3;
    } else {
        const int i2 = idx - QU;
        p = k + (size_t)i2 * 8;
        l = (i2 >> 3) & 2047;
        d0 = (i2 & 7) << 3;
    }
    s16x8 v = *(s16x8*)p;
    const float* tb = sct + l * 64 + (d0 & 31);
    const f4 ca = *(const f4*)(tb),      cb = *(const f4*)(tb + 4);
    const f4 sa = *(const f4*)(tb + 32), sb = *(const f4*)(tb + 36);
    const float ce[4] = { ca[0], ca[2], cb[0], cb[2] };
    const float co[4] = { ca[1], ca[3], cb[1], cb[3] };
    const float se[4] = { sa[0], sa[2], sb[0], sb[2] };
    const float so[4] = { sa[1], sa[3], sb[1], sb[3] };
    s16x8 o;
#pragma unroll
    for (int j = 0; j < 4; ++j) {
        const float xe = bf2f((ushort)v[2 * j]), xo = bf2f((ushort)v[2 * j + 1]);
        o[2 * j]     = (short)f2bf(xe * ce[j] - xo * se[j]);
        o[2 * j + 1] = (short)f2bf(xo * co[j] + xe * so[j]);
    }
    *(s16x8*)p = o;
}

// ---------------------------------------------------------------------------
// Windowed flash attention, bf16 MFMA, no __syncthreads (unchanged structure;
// output now bf16).
// ---------------------------------------------------------------------------
__global__ __launch_bounds__(256, 3) void k_attn_win(
    const ushort* __restrict__ qb, const ushort* __restrict__ kb,
    const ushort* __restrict__ vtb, const int* __restrict__ gpos,
    ushort* __restrict__ aout)
{
    __shared__ ushort Pl[4][1024];

    const int tid  = threadIdx.x;
    const int wv   = tid >> 6, lane = tid & 63;
    const int lr   = lane & 15, lg = lane >> 4;
    const int qt = blockIdx.x, h = blockIdx.y, b = blockIdx.z;
    const int g  = h >> 2;
    const int q0w = (qt << 6) + (wv << 4);

    const ushort* qp = qb  + (((size_t)b * H_ + h) * L_ + q0w) * Hd_;
    const ushort* kp = kb  + ((size_t)b * G_ + g) * (size_t)L_ * Hd_;
    const ushort* vp = vtb + ((size_t)b * G_ + g) * (size_t)Hd_ * L_;
    char* pbase = (char*)&Pl[wv][0];

    const s16x8* qr = (const s16x8*)(qp + (size_t)lr * Hd_);
    const s16x8 qf0 = qr[lg], qf1 = qr[lg + 4];

    int gall[4];
#pragma unroll
    for (int j = 0; j < 4; ++j) gall[j] = gpos[j];
    const int myg = gall[lr & 3];
    int gvalid = 0;
    if (lr < 4) {
        bool dup = false;
        for (int j = 0; j < lr; ++j) dup = dup || (gall[j] == myg);
        gvalid = !dup;
    }

    f32x4 acc_o[4];
#pragma unroll
    for (int j = 0; j < 4; ++j) acc_o[j] = (f32x4)0.f;
    f32x4 mrun = (f32x4)(-INFINITY);
    f32x4 lrun = (f32x4)0.f;

    const int t_lo = (qt - 4 > 0) ? qt - 4 : 0;
    const int t_hi = (qt + 4 < (L_ >> 6) - 1) ? qt + 4 : (L_ >> 6) - 1;
    const int ntiles = t_hi - t_lo + 1;

    for (int tt = 0; tt <= ntiles; ++tt) {
        const bool isWin = (tt < ntiles);
        const int s0 = (t_lo + tt) << 6;

        f32x4 s[4];
        if (isWin) {
#pragma unroll
            for (int gk = 0; gk < 4; ++gk) {
                const s16x8* kr = (const s16x8*)(kp + ((size_t)s0 + gk * 16 + lr) * Hd_);
                s16x8 kf0 = kr[lg], kf1 = kr[lg + 4];
                f32x4 t = __builtin_amdgcn_mfma_f32_16x16x32_bf16(qf0, kf0, (f32x4)0.f, 0, 0, 0);
                s[gk]   = __builtin_amdgcn_mfma_f32_16x16x32_bf16(qf1, kf1, t, 0, 0, 0);
            }
        } else {
            const s16x8* kr = (const s16x8*)(kp + (size_t)myg * Hd_);
            s16x8 kf0 = kr[lg], kf1 = kr[lg + 4];
            f32x4 t = __builtin_amdgcn_mfma_f32_16x16x32_bf16(qf0, kf0, (f32x4)0.f, 0, 0, 0);
            s[0]    = __builtin_amdgcn_mfma_f32_16x16x32_bf16(qf1, kf1, t, 0, 0, 0);
            s[1] = (f32x4)0.f; s[2] = (f32x4)0.f; s[3] = (f32x4)0.f;
        }

#pragma unroll
        for (int gk = 0; gk < 4; ++gk) {
#pragma unroll
            for (int r = 0; r < 4; ++r) {
                const int qpos = q0w + lg * 4 + r;
                bool valid;
                if (isWin) {
                    const int dlt = qpos - (s0 + gk * 16 + lr);
                    valid = (dlt <= WIN_) && (dlt >= -WIN_);
                } else if (gk == 0) {
                    const int dlt = qpos - myg;
                    valid = gvalid && ((dlt > WIN_) || (dlt < -WIN_));
                } else {
                    valid = false;
                }
                if (!valid) s[gk][r] = -INFINITY;
            }
        }

        f32x4 al4;
#pragma unroll
        for (int r = 0; r < 4; ++r) {
            float mx = fmaxf(fmaxf(s[0][r], s[1][r]), fmaxf(s[2][r], s[3][r]));
            mx = fmaxf(mx, __shfl_xor(mx, 1));
            mx = fmaxf(mx, __shfl_xor(mx, 2));
            mx = fmaxf(mx, __shfl_xor(mx, 4));
            mx = fmaxf(mx, __shfl_xor(mx, 8));
            const float mn = fmaxf(mrun[r], mx);
            const float al = (mn == -INFINITY) ? 1.f : __expf(mrun[r] - mn);
            const int row = lg * 4 + r;
            const int swz = (row & 7) << 4;
            float rs = 0.f;
#pragma unroll
            for (int gk = 0; gk < 4; ++gk) {
                const float sv = s[gk][r];
                const float p = (sv == -INFINITY) ? 0.f : __expf(sv - mn);
                const int key = gk * 16 + lr;
                *(ushort*)(pbase + (((row << 7) + (key << 1)) ^ swz)) = f2bf(p);
                rs += p;
            }
            rs += __shfl_xor(rs, 1);
            rs += __shfl_xor(rs, 2);
            rs += __shfl_xor(rs, 4);
            rs += __shfl_xor(rs, 8);
            lrun[r] = lrun[r] * al + rs;
            mrun[r] = mn;
            al4[r] = al;
        }
#pragma unroll
        for (int j = 0; j < 4; ++j) acc_o[j] *= al4;

        const int pswz = (lr & 7) << 4;
        const s16x8 pa0 = *(const s16x8*)(pbase + (((lr << 7) + (lg << 4)) ^ pswz));
        if (isWin) {
            const s16x8 pa1 = *(const s16x8*)(pbase + (((lr << 7) + 64 + (lg << 4)) ^ pswz));
#pragma unroll
            for (int dg = 0; dg < 4; ++dg) {
                const s16x8* vr = (const s16x8*)(vp + (size_t)(dg * 16 + lr) * L_ + s0);
                s16x8 vb0 = vr[lg], vb1 = vr[lg + 4];
                acc_o[dg] = __builtin_amdgcn_mfma_f32_16x16x32_bf16(pa0, vb0, acc_o[dg], 0, 0, 0);
                acc_o[dg] = __builtin_amdgcn_mfma_f32_16x16x32_bf16(pa1, vb1, acc_o[dg], 0, 0, 0);
            }
        } else {
#pragma unroll
            for (int dg = 0; dg < 4; ++dg) {
                s16x8 vb0 = (s16x8)(short)0;
                if (lg == 0) {
#pragma unroll
                    for (int j = 0; j < 4; ++j)
                        vb0[j] = (short)vp[(size_t)(dg * 16 + lr) * L_ + gall[j]];
                }
                acc_o[dg] = __builtin_amdgcn_mfma_f32_16x16x32_bf16(pa0, vb0, acc_o[dg], 0, 0, 0);
            }
        }
    }

#pragma unroll
    for (int r = 0; r < 4; ++r) {
        const float inv = 1.f / lrun[r];
        const int qrow = q0w + lg * 4 + r;
        ushort* op = aout + (((size_t)b * L_ + qrow) * H_ + h) * Hd_;
#pragma unroll
        for (int dg = 0; dg < 4; ++dg) op[dg * 16 + lr] = f2bf(acc_o[dg][r] * inv);
    }
}

// ---------------------------------------------------------------------------
// Full-row attention for <=4 unique global query rows (bf16 out).
// ---------------------------------------------------------------------------
__global__ __launch_bounds__(256) void k_attn_global_rows(
    const ushort* __restrict__ q, const ushort* __restrict__ kg,
    const ushort* __restrict__ vt, const int* __restrict__ gpos,
    ushort* __restrict__ aout)
{
    __shared__ float qrow[64];
    __shared__ float Ps[L_];
    __shared__ float red[4];
    __shared__ float pacc[4][64];

    const int tid = threadIdx.x;
    const int wv = tid >> 6, lane = tid & 63;
    const int b = blockIdx.x >> 4;
    const int h = blockIdx.x & 15;
    const int g = h >> 2;
    const ushort* kbase = kg + ((size_t)b * G_ + g) * (size_t)L_ * Hd_;
    const ushort* vbase = vt + ((size_t)b * G_ + g) * (size_t)Hd_ * L_;

    for (int gi = 0; gi < 4; ++gi) {
        const int lq = gpos[gi];
        bool dup = false;
        for (int j = 0; j < gi; ++j) dup = dup || (gpos[j] == lq);
        if (dup) continue;

        __syncthreads();
        if (tid < 64) qrow[tid] = bf2f(q[(((size_t)b * H_ + h) * L_ + lq) * Hd_ + tid]);
        __syncthreads();

        float sc[8]; float lmax = -INFINITY;
#pragma unroll
        for (int c = 0; c < 8; ++c) {
            const int s = tid + (c << 8);
            const s16x8* kr = (const s16x8*)(kbase + (size_t)s * Hd_);
            float dot = 0.f;
#pragma unroll
            for (int d8 = 0; d8 < 8; ++d8) {
                s16x8 kv = kr[d8];
#pragma unroll
                for (int j = 0; j < 8; ++j) dot += qrow[d8 * 8 + j] * bf2f((ushort)kv[j]);
            }
            sc[c] = dot; lmax = fmaxf(lmax, dot);
        }
#pragma unroll
        for (int o = 32; o; o >>= 1) lmax = fmaxf(lmax, __shfl_xor(lmax, o));
        if (lane == 0) red[wv] = lmax;
        __syncthreads();
        const float M = fmaxf(fmaxf(red[0], red[1]), fmaxf(red[2], red[3]));
        __syncthreads();

        float ls = 0.f;
#pragma unroll
        for (int c = 0; c < 8; ++c) {
            const float p = __expf(sc[c] - M);
            Ps[tid + (c << 8)] = p;
            ls += p;
        }
#pragma unroll
        for (int o = 32; o; o >>= 1) ls += __shfl_xor(ls, o);
        if (lane == 0) red[wv] = ls;
        __syncthreads();
        const float S = red[0] + red[1] + red[2] + red[3];

        const int d = tid & 63, ch = tid >> 6;
        const ushort* vr = vbase + (size_t)d * L_ + (ch << 9);
        float a = 0.f;
        for (int s8 = 0; s8 < 64; ++s8) {
            s16x8 vv = ((const s16x8*)vr)[s8];
            const float* pp = &Ps[(ch << 9) + (s8 << 3)];
#pragma unroll
            for (int j = 0; j < 8; ++j) a += pp[j] * bf2f((ushort)vv[j]);
        }
        pacc[ch][d] = a;
        __syncthreads();
        if (tid < 64) {
            const float sum = pacc[0][tid] + pacc[1][tid] + pacc[2][tid] + pacc[3][tid];
            aout[(((size_t)b * L_ + lq) * H_ + h) * Hd_ + tid] = f2bf(sum / S);
        }
        __syncthreads();
    }
}

// ---------------------------------------------------------------------------
extern "C" void kernel_launch(void* const* d_in, const int* in_sizes, int n_in,
                              void* d_out, int out_size, void* d_ws, size_t ws_size,
                              hipStream_t stream)
{
    const float* x  = (const float*)d_in[0];
    const int*   gp = (const int*)d_in[1];
    const float* Wq = (const float*)d_in[2];
    const float* bq = (const float*)d_in[3];
    const float* Wk = (const float*)d_in[4];
    const float* bk = (const float*)d_in[5];
    const float* Wv = (const float*)d_in[6];
    const float* bv = (const float*)d_in[7];
    const float* Wo = (const float*)d_in[8];
    const float* bo = (const float*)d_in[9];
    float* out = (float*)d_out;

    // workspace layout (ushort units)
    ushort* xb   = (ushort*)d_ws;                       // 4M  (reused as awsb)
    ushort* awsb = xb;                                  // alias: attn out bf16
    ushort* qws  = xb  + (size_t)4194304;               // 4M
    ushort* kws  = qws + (size_t)4194304;               // 1M
    ushort* vtws = kws + (size_t)1048576;               // 1M
    ushort* Wt   = vtws + (size_t)1048576;              // 1.5M
    ushort* Wot  = Wt  + (size_t)1572864;               // 1M
    float*  sct  = (float*)(Wot + (size_t)1048576);     // 128K floats

    k_prep_x<<<dim3(4096), 256, 0, stream>>>(x, xb);
    k_prep_w<<<dim3(16, 16, 4), 256, 0, stream>>>(Wq, Wk, Wv, Wo, Wt, Wot);
    k_prep_sc<<<dim3(256), 256, 0, stream>>>(sct);

    k_gemm_bf16<<<dim3(32, 12), 256, 0, stream>>>(xb, Wt, 0, bq, bk, bv,
                                                  qws, kws, vtws, (float*)0);
    k_rope<<<dim3(2560), 256, 0, stream>>>(qws, kws, sct);

    k_attn_win<<<dim3(32, 16, 2), 256, 0, stream>>>(qws, kws, vtws, gp, awsb);
    k_attn_global_rows<<<dim3(32), 256, 0, stream>>>(qws, kws, vtws, gp, awsb);

    k_gemm_bf16<<<dim3(32, 8), 256, 0, stream>>>(awsb, Wot, 1, bo, (const float*)0,
                                                 (const float*)0,
                                                 (ushort*)0, (ushort*)0, (ushort*)0, out);
}

// Round 4
// 181.703 us; speedup vs baseline: 5.8508x; 1.2506x over previous
//
#include <hip/hip_runtime.h>
#include <math.h>

#define B_   2
#define L_   2048
#define D_   1024
#define H_   16
#define G_   4
#define Hd_  64
#define WIN_ 256

typedef float f4 __attribute__((ext_vector_type(4)));
typedef float f32x4 __attribute__((ext_vector_type(4)));
typedef short s16x8 __attribute__((ext_vector_type(8)));
typedef ushort u16x4 __attribute__((ext_vector_type(4)));

// ln(10000)/32
#define ROPE_LN 0.28782313662425575

__device__ __forceinline__ float bf2f(ushort u) {
    union { uint i; float f; } c; c.i = ((uint)u) << 16; return c.f;
}
__device__ __forceinline__ ushort f2bf(float f) {
    union { float f; uint i; } c; c.f = f;
    return (ushort)((c.i + 0x7FFFu + ((c.i >> 16) & 1u)) >> 16);
}

// async global->LDS 16B copy: lds dest is wave-uniform base + lane*16
__device__ __forceinline__ void async_copy16(const ushort* g, ushort* l) {
    __builtin_amdgcn_global_load_lds(
        (const __attribute__((address_space(1))) void*)g,
        (__attribute__((address_space(3))) void*)l,
        16, 0, 0);
}

// ---------------------------------------------------------------------------
// Prep: cast x (fp32 -> bf16)
// ---------------------------------------------------------------------------
__global__ __launch_bounds__(256) void k_prep_x(const float* __restrict__ x,
                                                ushort* __restrict__ xb)
{
    const int idx = blockIdx.x * 256 + threadIdx.x;
    f4 v = ((const f4*)x)[idx];
    u16x4 o;
    o[0] = f2bf(v[0]); o[1] = f2bf(v[1]); o[2] = f2bf(v[2]); o[3] = f2bf(v[3]);
    ((u16x4*)xb)[idx] = o;
}

// ---------------------------------------------------------------------------
// Prep: transpose+cast weights.  z=0:Wq z=1:Wk z=2:Wv -> Wt[1536][1024]
//                                z=3:Wo -> Wot[1024][1024]
// ---------------------------------------------------------------------------
__global__ __launch_bounds__(256) void k_prep_w(
    const float* __restrict__ Wq, const float* __restrict__ Wk,
    const float* __restrict__ Wv, const float* __restrict__ Wo,
    ushort* __restrict__ Wt, ushort* __restrict__ Wot)
{
    __shared__ __align__(16) float Ts[64][68];
    const int z = blockIdx.z;
    const float* W; ushort* dst; int N, rowoff;
    if (z == 0)      { W = Wq; N = 1024; dst = Wt;  rowoff = 0;    }
    else if (z == 1) { W = Wk; N = 256;  dst = Wt;  rowoff = 1024; }
    else if (z == 2) { W = Wv; N = 256;  dst = Wt;  rowoff = 1280; }
    else             { W = Wo; N = 1024; dst = Wot; rowoff = 0;    }
    const int k0 = blockIdx.x << 6;
    const int n0 = blockIdx.y << 6;
    if (n0 >= N) return;
    const int tid = threadIdx.x;
    const int rr = tid >> 4, cc4 = (tid & 15) << 2;
#pragma unroll
    for (int i = 0; i < 4; ++i) {
        const int r = rr + i * 16;
        *(f4*)&Ts[r][cc4] = *(const f4*)&W[(size_t)(k0 + r) * N + n0 + cc4];
    }
    __syncthreads();
#pragma unroll
    for (int i = 0; i < 4; ++i) {
        const int tr = rr + i * 16;
        u16x4 pk;
#pragma unroll
        for (int j = 0; j < 4; ++j) pk[j] = f2bf(Ts[cc4 + j][tr]);
        *(u16x4*)&dst[(size_t)(rowoff + n0 + tr) * 1024 + k0 + cc4] = pk;
    }
}

// ---------------------------------------------------------------------------
// Prep: RoPE sin/cos table  sct[l*64+m]=cos, sct[l*64+32+m]=sin
// ---------------------------------------------------------------------------
__global__ __launch_bounds__(256) void k_prep_sc(float* __restrict__ sct)
{
    const int idx = blockIdx.x * 256 + threadIdx.x;   // 64K
    const int l = idx >> 5, m = idx & 31;
    const float invf = (float)exp(-ROPE_LN * (double)m);
    const float a = (float)l * invf;
    sct[l * 64 + m]      = cosf(a);
    sct[l * 64 + 32 + m] = sinf(a);
}

// ---------------------------------------------------------------------------
// bf16 MFMA GEMM (m97 structure): C[M,N] = A[M,1024] @ Bt[N,1024]^T.
// 128x128 tile, BK=64, global_load_lds(16B) staging, XOR-slot swizzle:
//   LDS (r, col c) holds global k-slot  ss = c ^ (r&7)   (16B slots, 8/row)
// Write side: linear LDS dest, inverse-swizzled per-lane global source.
// mode 0: QKV epilogue (bias + RoPE from LDS table + scatter q/k/Vt bf16)
// mode 1: out-proj epilogue (bias + fp32 store)
// ---------------------------------------------------------------------------
__global__ __launch_bounds__(256) void k_gemm_bf16(
    const ushort* __restrict__ A, const ushort* __restrict__ Bt, int mode,
    const float* __restrict__ b0, const float* __restrict__ b1,
    const float* __restrict__ b2, const float* __restrict__ sct,
    ushort* __restrict__ qo, ushort* __restrict__ ko, ushort* __restrict__ vt,
    float* __restrict__ outp)
{
    __shared__ __align__(16) ushort LDSbuf[16384];    // As 8192 | Bs 8192 (32KB)
    ushort* As = LDSbuf;
    ushort* Bs = LDSbuf + 8192;

    const int tid = threadIdx.x;
    const int wv = tid >> 6, lane = tid & 63, lr = lane & 15, lg = lane >> 4;
    const int wm = wv >> 1, wn = wv & 1;
    const int rblk = blockIdx.x << 7, cblk = blockIdx.y << 7;

    // staging: 1024 slots (128 rows x 8 k-slots of 16B) per matrix.
    // wave wv, inst i covers slots [wv*256+i*64, +64): lane l -> slot base+l.
    const ushort* agp[4]; const ushort* bgp[4];
    ushort* alds[4]; ushort* blds[4];
#pragma unroll
    for (int i = 0; i < 4; ++i) {
        const int slot = wv * 256 + i * 64 + lane;
        const int r = slot >> 3, c = slot & 7;
        const int ss = c ^ (r & 7);
        agp[i] = A  + (size_t)(rblk + r) * 1024 + ss * 8;
        bgp[i] = Bt + (size_t)(cblk + r) * 1024 + ss * 8;
        alds[i] = As + (wv * 256 + i * 64) * 8;       // wave-uniform base
        blds[i] = Bs + (wv * 256 + i * 64) * 8;
    }

    f32x4 acc[4][4];
#pragma unroll
    for (int m = 0; m < 4; ++m)
#pragma unroll
        for (int n = 0; n < 4; ++n) acc[m][n] = (f32x4)0.f;

    for (int kt = 0; kt < 16; ++kt) {
        if (kt) __syncthreads();                       // done reading prev tile
        const int ko_ = kt * 64;
#pragma unroll
        for (int i = 0; i < 4; ++i) {
            async_copy16(agp[i] + ko_, alds[i]);
            async_copy16(bgp[i] + ko_, blds[i]);
        }
        __syncthreads();                               // drains vmcnt -> ready

#pragma unroll
        for (int ks = 0; ks < 2; ++ks) {
            s16x8 aF[4], bF[4];
#pragma unroll
            for (int m = 0; m < 4; ++m) {
                const int r = wm * 64 + m * 16 + lr;
                const int c = (ks * 4 + lg) ^ (r & 7);
                aF[m] = *(const s16x8*)&As[r * 64 + c * 8];
            }
#pragma unroll
            for (int n = 0; n < 4; ++n) {
                const int r = wn * 64 + n * 16 + lr;
                const int c = (ks * 4 + lg) ^ (r & 7);
                bF[n] = *(const s16x8*)&Bs[r * 64 + c * 8];
            }
            __builtin_amdgcn_s_setprio(1);
#pragma unroll
            for (int m = 0; m < 4; ++m)
#pragma unroll
                for (int n = 0; n < 4; ++n)
                    acc[m][n] = __builtin_amdgcn_mfma_f32_16x16x32_bf16(aF[m], bF[n], acc[m][n], 0, 0, 0);
            __builtin_amdgcn_s_setprio(0);
        }
    }

    // ---- epilogue ----
    if (mode == 0) {
        const bool dorope = (cblk < 1280);
        float* tab = (float*)LDSbuf;                   // 8192 floats = 32KB
        if (dorope) {
            __syncthreads();
            const float* srcT = sct + (size_t)(rblk & 2047) * 64;
            for (int i = tid; i < 2048; i += 256)
                ((f4*)tab)[i] = ((const f4*)srcT)[i];
            __syncthreads();
        }
#pragma unroll
        for (int m = 0; m < 4; ++m) {
            const int row0 = rblk + wm * 64 + m * 16 + (lg << 2);
            const int bb = row0 >> 11, l0 = row0 & 2047;
            const int ll0 = row0 - rblk;
#pragma unroll
            for (int n = 0; n < 4; ++n) {
                const int col = cblk + wn * 64 + n * 16 + lr;
                float v_[4];
                const float bi = (col < 1024) ? b0[col]
                               : (col < 1280) ? b1[col - 1024] : b2[col - 1280];
#pragma unroll
                for (int rg = 0; rg < 4; ++rg) v_[rg] = acc[m][n][rg] + bi;
                if (dorope) {
                    const int mI = col & 31;
                    const float sgn = (lr & 1) ? 1.f : -1.f;
#pragma unroll
                    for (int rg = 0; rg < 4; ++rg) {
                        const float part = __shfl_xor(v_[rg], 1);
                        const float c_ = tab[(ll0 + rg) * 64 + mI];
                        const float s_ = tab[(ll0 + rg) * 64 + 32 + mI];
                        v_[rg] = v_[rg] * c_ + sgn * part * s_;
                    }
                }
                if (col < 1024) {
                    const int h = col >> 6, d = col & 63;
                    ushort* p = qo + (((size_t)(bb * 16 + h)) * 2048 + l0) * 64 + d;
#pragma unroll
                    for (int rg = 0; rg < 4; ++rg)
                        p[(size_t)rg * 64] = f2bf(v_[rg] * 0.125f);
                } else if (col < 1280) {
                    const int cl = col - 1024, g = cl >> 6, d = cl & 63;
                    ushort* p = ko + (((size_t)(bb * 4 + g)) * 2048 + l0) * 64 + d;
#pragma unroll
                    for (int rg = 0; rg < 4; ++rg)
                        p[(size_t)rg * 64] = f2bf(v_[rg]);
                } else {
                    const int cl = col - 1280, g = cl >> 6, d = cl & 63;
                    u16x4 pk;
#pragma unroll
                    for (int rg = 0; rg < 4; ++rg) pk[rg] = f2bf(v_[rg]);
                    *(u16x4*)(vt + ((size_t)(bb * 4 + g) * 64 + d) * 2048 + l0) = pk;
                }
            }
        }
    } else {
#pragma unroll
        for (int m = 0; m < 4; ++m) {
            const int row0 = rblk + wm * 64 + m * 16 + (lg << 2);
#pragma unroll
            for (int n = 0; n < 4; ++n) {
                const int col = cblk + wn * 64 + n * 16 + lr;
                const float bi = b0[col];
#pragma unroll
                for (int rg = 0; rg < 4; ++rg)
                    outp[(size_t)(row0 + rg) * 1024 + col] = acc[m][n][rg] + bi;
            }
        }
    }
}

// ---------------------------------------------------------------------------
// Windowed flash attention, bf16 MFMA, software-pipelined:
// K frags double-buffered in registers (prefetched 1 tile ahead); V loads
// issued under softmax; mask only on edge tiles; no __syncthreads.
// ---------------------------------------------------------------------------
#define LOADK(KF0, KF1, S0_) do {                                             \
    _Pragma("unroll") for (int gk = 0; gk < 4; ++gk) {                        \
        const s16x8* kr_ = (const s16x8*)(kp + ((size_t)(S0_) + gk * 16 + lr) * 64); \
        KF0[gk] = kr_[lg]; KF1[gk] = kr_[lg + 4]; } } while (0)

#define PROCESS(C0, C1, N0, N1, T) do {                                       \
    const int s0_ = (t_lo + (T)) << 6;                                        \
    f32x4 s_[4];                                                              \
    __builtin_amdgcn_s_setprio(1);                                            \
    _Pragma("unroll") for (int gk = 0; gk < 4; ++gk) {                        \
        f32x4 t0_ = __builtin_amdgcn_mfma_f32_16x16x32_bf16(qf0, C0[gk], (f32x4)0.f, 0, 0, 0); \
        s_[gk]    = __builtin_amdgcn_mfma_f32_16x16x32_bf16(qf1, C1[gk], t0_, 0, 0, 0); \
    }                                                                         \
    __builtin_amdgcn_s_setprio(0);                                            \
    { const int tn_ = ((T) + 1 < ntiles) ? (T) + 1 : ntiles - 1;              \
      const int s0n_ = (t_lo + tn_) << 6;                                     \
      LOADK(N0, N1, s0n_); }                                                  \
    s16x8 vf0_[4], vf1_[4];                                                   \
    _Pragma("unroll") for (int dg = 0; dg < 4; ++dg) {                        \
        const s16x8* vr_ = (const s16x8*)(vp + (size_t)(dg * 16 + lr) * 2048 + s0_); \
        vf0_[dg] = vr_[lg]; vf1_[dg] = vr_[lg + 4]; }                         \
    if (s0_ < q0w - 241 || s0_ > q0w + 193) {                                 \
        _Pragma("unroll") for (int gk = 0; gk < 4; ++gk)                      \
        _Pragma("unroll") for (int r = 0; r < 4; ++r) {                       \
            const int qpos_ = q0w + lg * 4 + r;                               \
            const int dlt_ = qpos_ - (s0_ + gk * 16 + lr);                    \
            if (dlt_ > WIN_ || dlt_ < -WIN_) s_[gk][r] = -INFINITY;           \
        }                                                                     \
    }                                                                         \
    f32x4 al4_;                                                               \
    _Pragma("unroll") for (int r = 0; r < 4; ++r) {                           \
        float mx_ = fmaxf(fmaxf(s_[0][r], s_[1][r]), fmaxf(s_[2][r], s_[3][r])); \
        mx_ = fmaxf(mx_, __shfl_xor(mx_, 1));                                 \
        mx_ = fmaxf(mx_, __shfl_xor(mx_, 2));                                 \
        mx_ = fmaxf(mx_, __shfl_xor(mx_, 4));                                 \
        mx_ = fmaxf(mx_, __shfl_xor(mx_, 8));                                 \
        const float mn_ = fmaxf(mrun[r], mx_);                                \
        const float al_ = (mn_ == -INFINITY) ? 1.f : __expf(mrun[r] - mn_);   \
        const int row_ = lg * 4 + r;                                          \
        const int swz_ = (row_ & 7) << 4;                                     \
        float rs_ = 0.f;                                                      \
        _Pragma("unroll") for (int gk = 0; gk < 4; ++gk) {                    \
            const float sv_ = s_[gk][r];                                      \
            const float p_ = (sv_ == -INFINITY) ? 0.f : __expf(sv_ - mn_);    \
            *(ushort*)(pbase + (((row_ << 7) + ((gk * 16 + lr) << 1)) ^ swz_)) = f2bf(p_); \
            rs_ += p_;                                                        \
        }                                                                     \
        rs_ += __shfl_xor(rs_, 1); rs_ += __shfl_xor(rs_, 2);                 \
        rs_ += __shfl_xor(rs_, 4); rs_ += __shfl_xor(rs_, 8);                 \
        lrun[r] = lrun[r] * al_ + rs_; mrun[r] = mn_; al4_[r] = al_;          \
    }                                                                         \
    _Pragma("unroll") for (int j = 0; j < 4; ++j) acc_o[j] *= al4_;           \
    { const int pswz_ = (lr & 7) << 4;                                        \
      const s16x8 pa0_ = *(const s16x8*)(pbase + (((lr << 7) + (lg << 4)) ^ pswz_)); \
      const s16x8 pa1_ = *(const s16x8*)(pbase + (((lr << 7) + 64 + (lg << 4)) ^ pswz_)); \
      __builtin_amdgcn_s_setprio(1);                                          \
      _Pragma("unroll") for (int dg = 0; dg < 4; ++dg) {                      \
          acc_o[dg] = __builtin_amdgcn_mfma_f32_16x16x32_bf16(pa0_, vf0_[dg], acc_o[dg], 0, 0, 0); \
          acc_o[dg] = __builtin_amdgcn_mfma_f32_16x16x32_bf16(pa1_, vf1_[dg], acc_o[dg], 0, 0, 0); \
      }                                                                       \
      __builtin_amdgcn_s_setprio(0);                                          \
    }                                                                         \
} while (0)

__global__ __launch_bounds__(256, 3) void k_attn_win(
    const ushort* __restrict__ qb, const ushort* __restrict__ kb,
    const ushort* __restrict__ vtb, const int* __restrict__ gpos,
    ushort* __restrict__ aout)
{
    __shared__ ushort Pl[4][1024];

    const int tid  = threadIdx.x;
    const int wv   = tid >> 6, lane = tid & 63;
    const int lr   = lane & 15, lg = lane >> 4;
    const int qt = blockIdx.x, h = blockIdx.y, b = blockIdx.z;
    const int g  = h >> 2;
    const int q0w = (qt << 6) + (wv << 4);

    const ushort* qp = qb  + (((size_t)b * H_ + h) * L_ + q0w) * Hd_;
    const ushort* kp = kb  + ((size_t)b * G_ + g) * (size_t)L_ * Hd_;
    const ushort* vp = vtb + ((size_t)b * G_ + g) * (size_t)Hd_ * L_;
    char* pbase = (char*)&Pl[wv][0];

    const s16x8* qr = (const s16x8*)(qp + (size_t)lr * Hd_);
    const s16x8 qf0 = qr[lg], qf1 = qr[lg + 4];

    int gall[4];
#pragma unroll
    for (int j = 0; j < 4; ++j) gall[j] = gpos[j];
    const int myg = gall[lr & 3];
    int gvalid = 0;
    if (lr < 4) {
        bool dup = false;
        for (int j = 0; j < lr; ++j) dup = dup || (gall[j] == myg);
        gvalid = !dup;
    }

    f32x4 acc_o[4];
#pragma unroll
    for (int j = 0; j < 4; ++j) acc_o[j] = (f32x4)0.f;
    f32x4 mrun = (f32x4)(-INFINITY);
    f32x4 lrun = (f32x4)0.f;

    const int t_lo = (qt - 4 > 0) ? qt - 4 : 0;
    const int t_hi = (qt + 4 < (L_ >> 6) - 1) ? qt + 4 : (L_ >> 6) - 1;
    const int ntiles = t_hi - t_lo + 1;

    s16x8 kA0[4], kA1[4], kB0[4], kB1[4];
    LOADK(kA0, kA1, t_lo << 6);

    int tt = 0;
    for (;;) {
        PROCESS(kA0, kA1, kB0, kB1, tt);
        ++tt; if (tt >= ntiles) break;
        PROCESS(kB0, kB1, kA0, kA1, tt);
        ++tt; if (tt >= ntiles) break;
    }

    // ---- global-column pseudo-tile (keys outside the window) ----
    {
        f32x4 s[4];
        const s16x8* kr = (const s16x8*)(kp + (size_t)myg * 64);
        s16x8 kf0 = kr[lg], kf1 = kr[lg + 4];
        f32x4 t = __builtin_amdgcn_mfma_f32_16x16x32_bf16(qf0, kf0, (f32x4)0.f, 0, 0, 0);
        s[0]    = __builtin_amdgcn_mfma_f32_16x16x32_bf16(qf1, kf1, t, 0, 0, 0);
        s[1] = (f32x4)0.f; s[2] = (f32x4)0.f; s[3] = (f32x4)0.f;

#pragma unroll
        for (int gk = 0; gk < 4; ++gk)
#pragma unroll
            for (int r = 0; r < 4; ++r) {
                const int qpos = q0w + lg * 4 + r;
                bool valid = false;
                if (gk == 0) {
                    const int dlt = qpos - myg;
                    valid = gvalid && ((dlt > WIN_) || (dlt < -WIN_));
                }
                if (!valid) s[gk][r] = -INFINITY;
            }

        f32x4 al4;
#pragma unroll
        for (int r = 0; r < 4; ++r) {
            float mx = fmaxf(fmaxf(s[0][r], s[1][r]), fmaxf(s[2][r], s[3][r]));
            mx = fmaxf(mx, __shfl_xor(mx, 1));
            mx = fmaxf(mx, __shfl_xor(mx, 2));
            mx = fmaxf(mx, __shfl_xor(mx, 4));
            mx = fmaxf(mx, __shfl_xor(mx, 8));
            const float mn = fmaxf(mrun[r], mx);
            const float al = (mn == -INFINITY) ? 1.f : __expf(mrun[r] - mn);
            const int row = lg * 4 + r;
            const int swz = (row & 7) << 4;
            float rs = 0.f;
#pragma unroll
            for (int gk = 0; gk < 4; ++gk) {
                const float sv = s[gk][r];
                const float p = (sv == -INFINITY) ? 0.f : __expf(sv - mn);
                *(ushort*)(pbase + (((row << 7) + ((gk * 16 + lr) << 1)) ^ swz)) = f2bf(p);
                rs += p;
            }
            rs += __shfl_xor(rs, 1);
            rs += __shfl_xor(rs, 2);
            rs += __shfl_xor(rs, 4);
            rs += __shfl_xor(rs, 8);
            lrun[r] = lrun[r] * al + rs;
            mrun[r] = mn;
            al4[r] = al;
        }
#pragma unroll
        for (int j = 0; j < 4; ++j) acc_o[j] *= al4;

        const int pswz = (lr & 7) << 4;
        const s16x8 pa0 = *(const s16x8*)(pbase + (((lr << 7) + (lg << 4)) ^ pswz));
#pragma unroll
        for (int dg = 0; dg < 4; ++dg) {
            s16x8 vb0 = (s16x8)(short)0;
            if (lg == 0) {
#pragma unroll
                for (int j = 0; j < 4; ++j)
                    vb0[j] = (short)vp[(size_t)(dg * 16 + lr) * 2048 + gall[j]];
            }
            acc_o[dg] = __builtin_amdgcn_mfma_f32_16x16x32_bf16(pa0, vb0, acc_o[dg], 0, 0, 0);
        }
    }

#pragma unroll
    for (int r = 0; r < 4; ++r) {
        const float inv = 1.f / lrun[r];
        const int qrow = q0w + lg * 4 + r;
        ushort* op = aout + (((size_t)b * L_ + qrow) * H_ + h) * Hd_;
#pragma unroll
        for (int dg = 0; dg < 4; ++dg) op[dg * 16 + lr] = f2bf(acc_o[dg][r] * inv);
    }
}

// ---------------------------------------------------------------------------
// Full-row attention for the <=4 unique global query rows; gi = blockIdx.y.
// ---------------------------------------------------------------------------
__global__ __launch_bounds__(256) void k_attn_global_rows(
    const ushort* __restrict__ q, const ushort* __restrict__ kg,
    const ushort* __restrict__ vt, const int* __restrict__ gpos,
    ushort* __restrict__ aout)
{
    __shared__ float qrow[64];
    __shared__ float Ps[L_];
    __shared__ float red[4];
    __shared__ float pacc[4][64];

    const int tid = threadIdx.x;
    const int wv = tid >> 6, lane = tid & 63;
    const int b = blockIdx.x >> 4;
    const int h = blockIdx.x & 15;
    const int g = h >> 2;
    const int gi = blockIdx.y;
    const int lq = gpos[gi];
    for (int j = 0; j < gi; ++j)
        if (gpos[j] == lq) return;                    // duplicate -> done
    const ushort* kbase = kg + ((size_t)b * G_ + g) * (size_t)L_ * Hd_;
    const ushort* vbase = vt + ((size_t)b * G_ + g) * (size_t)Hd_ * L_;

    if (tid < 64) qrow[tid] = bf2f(q[(((size_t)b * H_ + h) * L_ + lq) * Hd_ + tid]);
    __syncthreads();

    float sc[8]; float lmax = -INFINITY;
#pragma unroll
    for (int c = 0; c < 8; ++c) {
        const int s = tid + (c << 8);
        const s16x8* kr = (const s16x8*)(kbase + (size_t)s * Hd_);
        float dot = 0.f;
#pragma unroll
        for (int d8 = 0; d8 < 8; ++d8) {
            s16x8 kv = kr[d8];
#pragma unroll
            for (int j = 0; j < 8; ++j) dot += qrow[d8 * 8 + j] * bf2f((ushort)kv[j]);
        }
        sc[c] = dot; lmax = fmaxf(lmax, dot);
    }
#pragma unroll
    for (int o = 32; o; o >>= 1) lmax = fmaxf(lmax, __shfl_xor(lmax, o));
    if (lane == 0) red[wv] = lmax;
    __syncthreads();
    const float M = fmaxf(fmaxf(red[0], red[1]), fmaxf(red[2], red[3]));
    __syncthreads();

    float ls = 0.f;
#pragma unroll
    for (int c = 0; c < 8; ++c) {
        const float p = __expf(sc[c] - M);
        Ps[tid + (c << 8)] = p;
        ls += p;
    }
#pragma unroll
    for (int o = 32; o; o >>= 1) ls += __shfl_xor(ls, o);
    if (lane == 0) red[wv] = ls;
    __syncthreads();
    const float S = red[0] + red[1] + red[2] + red[3];

    const int d = tid & 63, ch = tid >> 6;
    const ushort* vr = vbase + (size_t)d * L_ + (ch << 9);
    float a = 0.f;
    for (int s8 = 0; s8 < 64; ++s8) {
        s16x8 vv = ((const s16x8*)vr)[s8];
        const float* pp = &Ps[(ch << 9) + (s8 << 3)];
#pragma unroll
        for (int j = 0; j < 8; ++j) a += pp[j] * bf2f((ushort)vv[j]);
    }
    pacc[ch][d] = a;
    __syncthreads();
    if (tid < 64) {
        const float sum = pacc[0][tid] + pacc[1][tid] + pacc[2][tid] + pacc[3][tid];
        aout[(((size_t)b * L_ + lq) * H_ + h) * Hd_ + tid] = f2bf(sum / S);
    }
}

// ---------------------------------------------------------------------------
extern "C" void kernel_launch(void* const* d_in, const int* in_sizes, int n_in,
                              void* d_out, int out_size, void* d_ws, size_t ws_size,
                              hipStream_t stream)
{
    const float* x  = (const float*)d_in[0];
    const int*   gp = (const int*)d_in[1];
    const float* Wq = (const float*)d_in[2];
    const float* bq = (const float*)d_in[3];
    const float* Wk = (const float*)d_in[4];
    const float* bk = (const float*)d_in[5];
    const float* Wv = (const float*)d_in[6];
    const float* bv = (const float*)d_in[7];
    const float* Wo = (const float*)d_in[8];
    const float* bo = (const float*)d_in[9];
    float* out = (float*)d_out;

    // workspace layout (ushort units)
    ushort* xb   = (ushort*)d_ws;                       // 4M (reused as awsb)
    ushort* awsb = xb;
    ushort* qws  = xb  + (size_t)4194304;               // 4M
    ushort* kws  = qws + (size_t)4194304;               // 1M
    ushort* vtws = kws + (size_t)1048576;               // 1M
    ushort* Wt   = vtws + (size_t)1048576;              // 1.5M
    ushort* Wot  = Wt  + (size_t)1572864;               // 1M
    float*  sct  = (float*)(Wot + (size_t)1048576);     // 128K floats

    k_prep_x<<<dim3(4096), 256, 0, stream>>>(x, xb);
    k_prep_w<<<dim3(16, 16, 4), 256, 0, stream>>>(Wq, Wk, Wv, Wo, Wt, Wot);
    k_prep_sc<<<dim3(256), 256, 0, stream>>>(sct);

    k_gemm_bf16<<<dim3(32, 12), 256, 0, stream>>>(xb, Wt, 0, bq, bk, bv, sct,
                                                  qws, kws, vtws, (float*)0);

    k_attn_win<<<dim3(32, 16, 2), 256, 0, stream>>>(qws, kws, vtws, gp, awsb);
    k_attn_global_rows<<<dim3(32, 4), 256, 0, stream>>>(qws, kws, vtws, gp, awsb);

    k_gemm_bf16<<<dim3(32, 8), 256, 0, stream>>>(awsb, Wot, 1, bo, (const float*)0,
                                                 (const float*)0, (const float*)0,
                                                 (ushort*)0, (ushort*)0, (ushort*)0, out);
}